// Round 10
// baseline (230.838 us; speedup 1.0000x reference)
//
#include <hip/hip_runtime.h>

#define DIM 512
#define WAVE 64
#define WPB 4
#define RSER 8                        // rows streamed per wave
#define BLOCK (WAVE * WPB)
#define ROWS_PER_BLOCK (WPB * RSER)   // 32

typedef float vfloat4 __attribute__((ext_vector_type(4)));

// fire-and-forget 16B load; asm def = non-rematerializable (r8 technique).
// "memory" clobber pins issue order vs stores -> vmcnt accounting is exact.
__device__ __forceinline__ vfloat4 ga_load16(const float* p) {
    vfloat4 r;
    asm volatile("global_load_dwordx4 %0, %1, off" : "=v"(r) : "v"(p) : "memory");
    return r;
}

// ---- DS-free 64-lane butterflies (r4-proven) -------------------------------
#define DPPF(x, ctrl) __int_as_float(__builtin_amdgcn_update_dpp( \
    __float_as_int(x), __float_as_int(x), (ctrl), 0xf, 0xf, false))

__device__ __forceinline__ float red16_sum(float x) {
    x += DPPF(x, 0xB1);
    x += DPPF(x, 0x4E);
    x += DPPF(x, 0x124);
    x += DPPF(x, 0x128);
    return x;
}
__device__ __forceinline__ float red16_max(float x) {
    x = fmaxf(x, DPPF(x, 0xB1));
    x = fmaxf(x, DPPF(x, 0x4E));
    x = fmaxf(x, DPPF(x, 0x124));
    x = fmaxf(x, DPPF(x, 0x128));
    return x;
}
__device__ __forceinline__ float xswap16_sum(float x) {
    float t = x, u = x;
    asm("" : "+v"(u));
    asm("v_permlane16_swap_b32 %0, %1" : "+v"(t), "+v"(u));
    return t + u;
}
__device__ __forceinline__ float xswap32_sum(float x) {
    float t = x, u = x;
    asm("" : "+v"(u));
    asm("v_permlane32_swap_b32 %0, %1" : "+v"(t), "+v"(u));
    return t + u;
}
__device__ __forceinline__ float xswap16_max(float x) {
    float t = x, u = x;
    asm("" : "+v"(u));
    asm("v_permlane16_swap_b32 %0, %1" : "+v"(t), "+v"(u));
    return fmaxf(t, u);
}
__device__ __forceinline__ float xswap32_max(float x) {
    float t = x, u = x;
    asm("" : "+v"(u));
    asm("v_permlane32_swap_b32 %0, %1" : "+v"(t), "+v"(u));
    return fmaxf(t, u);
}
__device__ __forceinline__ float allred_sum(float x) {
    return xswap32_sum(xswap16_sum(red16_sum(x)));
}
__device__ __forceinline__ float allred_max(float x) {
    return xswap32_max(xswap16_max(red16_max(x)));
}

// ---- one row: max-init Michelot fixed point + store ------------------------
__device__ __forceinline__ void process_row(vfloat4 a, vfloat4 b,
                                            float* orow, int lane) {
    float z[8] = {a.x, a.y, a.z, a.w, b.x, b.y, b.z, b.w};

    float m = fmaxf(fmaxf(fmaxf(z[0], z[1]), fmaxf(z[2], z[3])),
                    fmaxf(fmaxf(z[4], z[5]), fmaxf(z[6], z[7])));
    m = allred_max(m);
    float tau = m - 1.0f;   // valid lower bound (p_max <= 1)

    int kprev = 0;
    for (int it = 0; it < 32; ++it) {
        float S = 0.f;
        int   K = 0;
#pragma unroll
        for (int j = 0; j < 8; ++j) {
            const bool in = z[j] > tau;
            S += in ? z[j] : 0.f;
            K += (int)__popcll(__ballot(in));
        }
        S = allred_sum(S);
        if (K == kprev) break;  // wave-uniform; K stable <=> fixed point
        kprev = K;
        tau = (S - 1.0f) * __builtin_amdgcn_rcpf((float)K);  // K >= 1 always
    }

    float4 oa, ob;
    oa.x = fmaxf(0.f, z[0] - tau);
    oa.y = fmaxf(0.f, z[1] - tau);
    oa.z = fmaxf(0.f, z[2] - tau);
    oa.w = fmaxf(0.f, z[3] - tau);
    ob.x = fmaxf(0.f, z[4] - tau);
    ob.y = fmaxf(0.f, z[5] - tau);
    ob.z = fmaxf(0.f, z[6] - tau);
    ob.w = fmaxf(0.f, z[7] - tau);
    float4* o4 = reinterpret_cast<float4*>(orow);
    o4[lane]        = oa;
    o4[lane + WAVE] = ob;
}

__global__ __launch_bounds__(BLOCK, 8) void sparsemax_kernel(
    const float* __restrict__ x, float* __restrict__ out, int batch) {
    // Convoy diagnosis (r0-r9): VALU time (~27us) and memory time (~43us) add
    // in series (~70us measured) because cohort-launched short blocks load /
    // compute / exit in phase. Fix: each wave streams 8 rows with a register
    // double-buffer; loads for row r+2 issue right after row r's stores and
    // are waited on only after row r+1's full compute phase -> memory issue
    // is continuous under compute, independent of cross-wave desync.
    const int lane = threadIdx.x & 63;
    const long wrow = ((long)blockIdx.x * WPB + (threadIdx.x >> 6)) * RSER;
    if (wrow >= batch) return;
    const float* xb = x + wrow * DIM + 4 * lane;   // per-lane base
    float*       ob = out + wrow * DIM;

    // prologue: rows 0,1 in flight; wait only for row 0
    vfloat4 A0 = ga_load16(xb);
    vfloat4 B0 = ga_load16(xb + 256);
    vfloat4 A1 = ga_load16(xb + DIM);
    vfloat4 B1 = ga_load16(xb + DIM + 256);
    asm volatile("s_waitcnt vmcnt(2)" : "+v"(A0), "+v"(B0) :: "memory");

    // vmcnt bookkeeping (in-order retirement), steady state at end of iter r:
    // in flight = [stores r (2), loads r+2 (2)] -> wait vmcnt(4) retires
    // {stores r-1, loads r+1}; tail: vmcnt(2), then none.
#define STEP(r, CA, CB, NA, NB)                                               \
    process_row(CA, CB, ob + (r) * DIM, lane);                                \
    if ((r) + 2 < RSER) {                                                     \
        CA = ga_load16(xb + ((r) + 2) * DIM);                                 \
        CB = ga_load16(xb + ((r) + 2) * DIM + 256);                           \
        asm volatile("s_waitcnt vmcnt(4)" : "+v"(NA), "+v"(NB) :: "memory");  \
    } else if ((r) + 1 < RSER) {                                              \
        asm volatile("s_waitcnt vmcnt(2)" : "+v"(NA), "+v"(NB) :: "memory");  \
    }

    STEP(0, A0, B0, A1, B1)
    STEP(1, A1, B1, A0, B0)
    STEP(2, A0, B0, A1, B1)
    STEP(3, A1, B1, A0, B0)
    STEP(4, A0, B0, A1, B1)
    STEP(5, A1, B1, A0, B0)
    STEP(6, A0, B0, A1, B1)
    STEP(7, A1, B1, A0, B0)
#undef STEP
}

extern "C" void kernel_launch(void* const* d_in, const int* in_sizes, int n_in,
                              void* d_out, int out_size, void* d_ws, size_t ws_size,
                              hipStream_t stream) {
    const float* x = (const float*)d_in[0];
    float* out     = (float*)d_out;
    const int batch = in_sizes[0] / DIM;  // 65536
    const int grid  = (batch + ROWS_PER_BLOCK - 1) / ROWS_PER_BLOCK;  // 2048
    sparsemax_kernel<<<grid, BLOCK, 0, stream>>>(x, out, batch);
}

// Round 11
// 227.022 us; speedup vs baseline: 1.0168x; 1.0168x over previous
//
#include <hip/hip_runtime.h>

#define DIM 512
#define WAVE 64
#define WPB 4
#define BLOCK (WAVE * WPB)

typedef float vfloat4 __attribute__((ext_vector_type(4)));

// non-rematerializable 16B load (r8): asm def must stay register-resident
__device__ __forceinline__ vfloat4 ga_load16(const float* p) {
    vfloat4 r;
    asm volatile("global_load_dwordx4 %0, %1, off" : "=v"(r) : "v"(p));
    return r;
}

// ---- DS-free 64-lane butterflies (r4-proven) -------------------------------
#define DPPF(x, ctrl) __int_as_float(__builtin_amdgcn_update_dpp( \
    __float_as_int(x), __float_as_int(x), (ctrl), 0xf, 0xf, false))

__device__ __forceinline__ float red16_sum(float x) {
    x += DPPF(x, 0xB1);   // quad_perm xor1
    x += DPPF(x, 0x4E);   // quad_perm xor2
    x += DPPF(x, 0x124);  // row_ror:4
    x += DPPF(x, 0x128);  // row_ror:8
    return x;
}
__device__ __forceinline__ float red16_max(float x) {
    x = fmaxf(x, DPPF(x, 0xB1));
    x = fmaxf(x, DPPF(x, 0x4E));
    x = fmaxf(x, DPPF(x, 0x124));
    x = fmaxf(x, DPPF(x, 0x128));
    return x;
}
__device__ __forceinline__ float xswap16_sum(float x) {
    float t = x, u = x;
    asm("" : "+v"(u));
    asm("v_permlane16_swap_b32 %0, %1" : "+v"(t), "+v"(u));
    return t + u;
}
__device__ __forceinline__ float xswap32_sum(float x) {
    float t = x, u = x;
    asm("" : "+v"(u));
    asm("v_permlane32_swap_b32 %0, %1" : "+v"(t), "+v"(u));
    return t + u;
}
__device__ __forceinline__ float xswap16_max(float x) {
    float t = x, u = x;
    asm("" : "+v"(u));
    asm("v_permlane16_swap_b32 %0, %1" : "+v"(t), "+v"(u));
    return fmaxf(t, u);
}
__device__ __forceinline__ float xswap32_max(float x) {
    float t = x, u = x;
    asm("" : "+v"(u));
    asm("v_permlane32_swap_b32 %0, %1" : "+v"(t), "+v"(u));
    return fmaxf(t, u);
}
__device__ __forceinline__ float allred_sum(float x) {
    return xswap32_sum(xswap16_sum(red16_sum(x)));
}
__device__ __forceinline__ float allred_max(float x) {
    return xswap32_max(xswap16_max(red16_max(x)));
}

__global__ __launch_bounds__(BLOCK) void sparsemax_kernel(
    const float* __restrict__ x, float* __restrict__ out, int batch) {
    // r8 structure (best measured: 224.2us). Single change: WARM-START tau0.
    // Theorem: one Michelot update from ANY threshold t (nonempty set) gives
    // g(t) = (S_t-1)/K_t <= tau*  [subset A of support: S_A-1 = |A|tau* +
    // (sum_A p - 1) <= |A|tau*; superset: extras contribute z-tau* <= 0].
    // And for tau <= tau*: f(tau)=sum(z-tau)_+ >= 1  =>  g(tau) >= tau, so
    // the iteration is monotone with nested sets; K-stability remains a sound
    // exact termination test (first transition nested too: tau1 <= tau* < t
    // widens the set). Hence a data-informed guess t=2.3 (iid N(0,1), D=512:
    // tau* ~ 2.3-2.5, K* ~ 4-6) is EXACT regardless of the data; it only
    // changes iteration count (~5-6 from m-1 -> ~3).
    const int row  = blockIdx.x * WPB + (threadIdx.x >> 6);
    const int lane = threadIdx.x & 63;
    if (row >= batch) return;

    const float* xr = x + (size_t)row * DIM;
    vfloat4 a = ga_load16(xr + 4 * lane);
    vfloat4 b = ga_load16(xr + 4 * lane + 256);
    asm volatile("s_waitcnt vmcnt(0)" : "+v"(a), "+v"(b) :: "memory");

    float z[8] = {a.x, a.y, a.z, a.w, b.x, b.y, b.z, b.w};

    // row max (still needed for the nonempty-set guard)
    float m = fmaxf(fmaxf(fmaxf(z[0], z[1]), fmaxf(z[2], z[3])),
                    fmaxf(fmaxf(z[4], z[5]), fmaxf(z[6], z[7])));
    m = allred_max(m);

    // warm start: t = min(2.3, m - 0.25) -> set nonempty by construction
    // (t = 2.3 only when m >= 2.55; else t = m - 0.25 keeps the max in-set)
    float tau = fminf(2.3f, m - 0.25f);

    int kprev = 0;
    for (int it = 0; it < 32; ++it) {
        float S = 0.f;
        int   K = 0;
#pragma unroll
        for (int j = 0; j < 8; ++j) {
            const bool in = z[j] > tau;
            S += in ? z[j] : 0.f;
            K += (int)__popcll(__ballot(in));
        }
        S = allred_sum(S);
        if (K == kprev) break;  // wave-uniform; nested sets -> sound
        kprev = K;
        tau = (S - 1.0f) * __builtin_amdgcn_rcpf((float)K);  // K >= 1 always
    }

    // epilogue: out = max(0, z - tau)
    float4 oa, ob;
    oa.x = fmaxf(0.f, z[0] - tau);
    oa.y = fmaxf(0.f, z[1] - tau);
    oa.z = fmaxf(0.f, z[2] - tau);
    oa.w = fmaxf(0.f, z[3] - tau);
    ob.x = fmaxf(0.f, z[4] - tau);
    ob.y = fmaxf(0.f, z[5] - tau);
    ob.z = fmaxf(0.f, z[6] - tau);
    ob.w = fmaxf(0.f, z[7] - tau);
    float4* orow = reinterpret_cast<float4*>(out) + (size_t)row * (DIM / 4);
    orow[lane]        = oa;
    orow[lane + WAVE] = ob;
}

extern "C" void kernel_launch(void* const* d_in, const int* in_sizes, int n_in,
                              void* d_out, int out_size, void* d_ws, size_t ws_size,
                              hipStream_t stream) {
    const float* x = (const float*)d_in[0];
    float* out     = (float*)d_out;
    const int batch = in_sizes[0] / DIM;  // 65536
    const int grid  = (batch + WPB - 1) / WPB;
    sparsemax_kernel<<<grid, BLOCK, 0, stream>>>(x, out, batch);
}